// Round 4
// baseline (108.433 us; speedup 1.0000x reference)
//
#include <hip/hip_runtime.h>
#include <math.h>

// ScoreNet: B=8, NV=512, C=256, H=6, R=32, PAIR_H=16, RBF_K=8
// Pipeline:
//  k_x:     x[4096][256] = pooled feats
//  k_pack:  Wcat[256][448] = [Wq/sqrt(R) | sp*Wpi | Wk | Wpj | dW | pad], bcat[448]
//  k_uv:    GEMM x @ Wcat -> U[4096][208], V[4096][208], dv[4096]
//  k_gemm:  S_lin[b][n][m] = U[b,n,:] . V[b,m,:]  -> written to d_out
//  k_pairs: per-pair geom/angle MLPs, diag, logit scale; in-place on d_out

#define NCAT 448
#define NCAT_REAL 417
#define UCOLS 208

__device__ __forceinline__ float sigmoidf_(float x){ return 1.0f/(1.0f + __expf(-x)); }

__global__ __launch_bounds__(256) void k_x(const float* __restrict__ feats, float* __restrict__ x){
    int row = blockIdx.x;            // b*512 + n
    int b = row >> 9, n = row & 511;
    size_t base = ((size_t)(b*1025 + 1 + 2*n))*256 + threadIdx.x;
    x[(size_t)row*256 + threadIdx.x] = 0.5f*(feats[base] + feats[base+256]);
}

__global__ __launch_bounds__(256) void k_pack(const float* __restrict__ Wq, const float* __restrict__ Wk,
        const float* __restrict__ Wpi, const float* __restrict__ bpi,
        const float* __restrict__ Wpj, const float* __restrict__ bpj,
        const float* __restrict__ dW, const float* __restrict__ db,
        const float* __restrict__ a_pair,
        float* __restrict__ Wcat, float* __restrict__ bcat){
    int idx = blockIdx.x*256 + threadIdx.x;   // 0 .. 114687 (= 256*448)
    int c = idx / NCAT;
    int col = idx - c*NCAT;
    float sp = 1.5f * sigmoidf_(a_pair[0]);
    const float invSqrtR = 0.17677669529663687f; // 1/sqrt(32)
    float v;
    if      (col < 192) v = Wq[c*192 + col] * invSqrtR;
    else if (col < 208) v = sp * Wpi[c*16 + (col-192)];
    else if (col < 400) v = Wk[c*192 + (col-208)];
    else if (col < 416) v = Wpj[c*16 + (col-400)];
    else if (col == 416) v = dW[c];
    else v = 0.f;
    Wcat[idx] = v;
    if (idx < NCAT){
        float bv = 0.f;
        if      (idx >= 192 && idx < 208) bv = sp * bpi[idx-192];
        else if (idx >= 400 && idx < 416) bv = bpj[idx-400];
        else if (idx == 416)              bv = db[0];
        bcat[idx] = bv;
    }
}

// x[4096][256] @ Wcat[256][448] with routing epilogue -> U, V, dv
__global__ __launch_bounds__(256) void k_uv(const float* __restrict__ x, const float* __restrict__ Wcat,
        const float* __restrict__ bcat, float* __restrict__ U, float* __restrict__ V, float* __restrict__ dv){
    __shared__ float Xs[16][68];
    __shared__ float Ws[16][68];
    int tid = threadIdx.x;
    int c0 = blockIdx.x*64, r0 = blockIdx.y*64;
    int tx = tid & 15, ty = tid >> 4;
    int lr = tid >> 2, lk = (tid & 3)*4;     // x-tile loader
    int lc = tid & 63, lkw = tid >> 6;       // W-tile loader
    float acc[4][4] = {};
    for (int k0 = 0; k0 < 256; k0 += 16){
        float4 xa = *(const float4*)(x + (size_t)(r0+lr)*256 + k0 + lk);
        float wv[4];
        #pragma unroll
        for (int j = 0; j < 4; j++) wv[j] = Wcat[(size_t)(k0 + lkw + j*4)*NCAT + c0 + lc];
        __syncthreads();
        Xs[lk+0][lr]=xa.x; Xs[lk+1][lr]=xa.y; Xs[lk+2][lr]=xa.z; Xs[lk+3][lr]=xa.w;
        #pragma unroll
        for (int j = 0; j < 4; j++) Ws[lkw + j*4][lc] = wv[j];
        __syncthreads();
        #pragma unroll
        for (int k = 0; k < 16; k++){
            float4 a  = *(const float4*)&Xs[k][ty*4];
            float4 bb = *(const float4*)&Ws[k][tx*4];
            float av[4] = {a.x,a.y,a.z,a.w};
            float bv[4] = {bb.x,bb.y,bb.z,bb.w};
            #pragma unroll
            for (int i = 0; i < 4; i++)
                #pragma unroll
                for (int j = 0; j < 4; j++)
                    acc[i][j] += av[i]*bv[j];
        }
    }
    #pragma unroll
    for (int i = 0; i < 4; i++){
        int row = r0 + ty*4 + i;
        #pragma unroll
        for (int j = 0; j < 4; j++){
            int col = c0 + tx*4 + j;
            if (col >= NCAT_REAL) continue;
            float v = acc[i][j] + bcat[col];
            if (col < 208){
                if (col >= 192) v = fmaxf(v, 0.f);
                U[(size_t)row*UCOLS + col] = v;
            } else if (col < 416){
                int cc = col - 208;
                if (cc >= 192) v = fmaxf(v, 0.f);
                V[(size_t)row*UCOLS + cc] = v;
            } else {
                dv[row] = v;
            }
        }
    }
}

// S_lin[b][n][m] = sum_k U[b,n,k]*V[b,m,k]
__global__ __launch_bounds__(256) void k_gemm(const float* __restrict__ U, const float* __restrict__ V,
                                              float* __restrict__ S){
    __shared__ float Us[16][68];
    __shared__ float Vs[16][68];
    int tid = threadIdx.x;
    int b = blockIdx.z;
    int m0 = blockIdx.x*64, n0 = blockIdx.y*64;
    const float* Ub = U + ((size_t)b*512 + n0)*UCOLS;
    const float* Vb = V + ((size_t)b*512 + m0)*UCOLS;
    int tx = tid & 15, ty = tid >> 4;
    int lr = tid >> 2, lk = (tid & 3)*4;
    float acc[4][4] = {};
    for (int k0 = 0; k0 < 208; k0 += 16){
        float4 ua = *(const float4*)(Ub + (size_t)lr*UCOLS + k0 + lk);
        float4 va = *(const float4*)(Vb + (size_t)lr*UCOLS + k0 + lk);
        __syncthreads();
        Us[lk+0][lr]=ua.x; Us[lk+1][lr]=ua.y; Us[lk+2][lr]=ua.z; Us[lk+3][lr]=ua.w;
        Vs[lk+0][lr]=va.x; Vs[lk+1][lr]=va.y; Vs[lk+2][lr]=va.z; Vs[lk+3][lr]=va.w;
        __syncthreads();
        #pragma unroll
        for (int k = 0; k < 16; k++){
            float4 a  = *(const float4*)&Us[k][ty*4];
            float4 bb = *(const float4*)&Vs[k][tx*4];
            float av[4] = {a.x,a.y,a.z,a.w};
            float bv[4] = {bb.x,bb.y,bb.z,bb.w};
            #pragma unroll
            for (int i = 0; i < 4; i++)
                #pragma unroll
                for (int j = 0; j < 4; j++)
                    acc[i][j] += av[i]*bv[j];
        }
    }
    float* Sp = S + ((size_t)b*512 + n0 + ty*4)*512 + m0 + tx*4;
    #pragma unroll
    for (int i = 0; i < 4; i++)
        *(float4*)(Sp + (size_t)i*512) = make_float4(acc[i][0], acc[i][1], acc[i][2], acc[i][3]);
}

// per-pair geom + angle MLPs; in-place on S (d_out)
__global__ __launch_bounds__(256) void k_pairs(const float* __restrict__ xy,
        const float* __restrict__ gW1, const float* __restrict__ gb1,
        const float* __restrict__ gW2, const float* __restrict__ gb2,
        const float* __restrict__ aW1, const float* __restrict__ ab1,
        const float* __restrict__ aW2, const float* __restrict__ ab2,
        const float* __restrict__ dv,
        const float* __restrict__ a_geom, const float* __restrict__ a_ang,
        const float* __restrict__ lsc,
        float* __restrict__ S){
    __shared__ __attribute__((aligned(16))) float gw1t[32][12]; // transposed gW1
    __shared__ float gb1s[32], gw2s[32];
    __shared__ __attribute__((aligned(16))) float aw1t[16][8];  // transposed aW1 (padded)
    __shared__ float ab1s[16], aw2s[16];
    int tid = threadIdx.x;
    for (int i = tid; i < 384; i += 256){ int h = i & 31, dd = i >> 5; gw1t[h][dd] = gW1[dd*32 + h]; }
    if (tid < 32){ gb1s[tid] = gb1[tid]; gw2s[tid] = gW2[tid]; }
    if (tid < 96){ int h = tid & 15, dd = tid >> 4; aw1t[h][dd] = aW1[dd*16 + h]; }
    else if (tid < 112){ ab1s[tid-96] = ab1[tid-96]; }
    else if (tid < 128){ aw2s[tid-112] = aW2[tid-112]; }
    __syncthreads();

    float sg = 1.5f*sigmoidf_(a_geom[0]);
    float sa = 1.5f*sigmoidf_(a_ang[0]);
    float ls = 0.5f + 2.5f*sigmoidf_(lsc[0]);

    int flat0 = (blockIdx.x*256 + tid)*4;
    int m0 = flat0 & 511;
    int n  = (flat0 >> 9) & 511;
    int b  = flat0 >> 18;
    const float* xyb = xy + (size_t)b*1024;
    float2 pn = *(const float2*)(xyb + 2*n);
    float yn = pn.x, xn = pn.y;
    bool padn = (fabsf(yn) < 1e-9f) && (fabsf(xn) < 1e-9f);
    float4 q0 = *(const float4*)(xyb + 2*m0);
    float4 q1 = *(const float4*)(xyb + 2*m0 + 4);
    float ym[4] = {q0.x, q0.z, q1.x, q1.z};
    float xm[4] = {q0.y, q0.w, q1.y, q1.w};

    float dy[4], dx[4], c1[4], s1[4], c2[4], s2[4], c4[4], s4[4];
    float ph[4][8];
    bool padp[4];
    const float MU = 0.20203051f;       // sqrt(2)/7 (f32)
    const float GAMMA = 12.2499985f;    // 1/(2*MU^2 + 1e-8)
    #pragma unroll
    for (int p = 0; p < 4; p++){
        float dyp = yn - ym[p], dxp = xn - xm[p];
        dy[p] = dyp; dx[p] = dxp;
        bool padm = (fabsf(ym[p]) < 1e-9f) && (fabsf(xm[p]) < 1e-9f);
        padp[p] = padn || padm;
        float r2 = dyp*dyp + dxp*dxp;
        float re = sqrtf(r2 + 1e-8f);
        float c, s;
        if (r2 > 0.f){ float inv = rsqrtf(r2); c = dxp*inv; s = dyp*inv; }
        else { c = 1.f; s = 0.f; }   // atan2(0,0) = 0
        c1[p] = c; s1[p] = s;
        float cc2 = c*c - s*s, ss2 = 2.f*c*s;
        c2[p] = cc2; s2[p] = ss2;
        c4[p] = cc2*cc2 - ss2*ss2; s4[p] = 2.f*cc2*ss2;
        #pragma unroll
        for (int k = 0; k < 8; k++){
            float t = re - (float)k*MU;
            ph[p][k] = __expf(-GAMMA*t*t);
        }
    }

    float accG[4] = {0,0,0,0}, accA[4] = {0,0,0,0};
    for (int h = 0; h < 32; h++){
        const float4* wrow = (const float4*)&gw1t[h][0];
        float4 w0 = wrow[0], w1 = wrow[1], w2q = wrow[2];
        float bb = gb1s[h], w2 = gw2s[h];
        #pragma unroll
        for (int p = 0; p < 4; p++){
            float s = bb + dy[p]*w0.x + dx[p]*w0.y + ph[p][0]*w0.z + ph[p][1]*w0.w
                    + ph[p][2]*w1.x + ph[p][3]*w1.y + ph[p][4]*w1.z + ph[p][5]*w1.w
                    + ph[p][6]*w2q.x + ph[p][7]*w2q.y + c1[p]*w2q.z + s1[p]*w2q.w;
            accG[p] += w2 * fmaxf(s, 0.f);
        }
    }
    for (int h = 0; h < 16; h++){
        const float4* ar = (const float4*)&aw1t[h][0];
        float4 a0 = ar[0];
        float2 a1 = *(const float2*)&aw1t[h][4];
        float bb = ab1s[h], w2 = aw2s[h];
        #pragma unroll
        for (int p = 0; p < 4; p++){
            float s = bb + c1[p]*a0.x + s1[p]*a0.y + c2[p]*a0.z + s2[p]*a0.w
                    + c4[p]*a1.x + s4[p]*a1.y;
            accA[p] += w2 * fmaxf(s, 0.f);
        }
    }

    float gb2v = gb2[0], ab2v = ab2[0];
    float4 sl = *(const float4*)(S + (size_t)flat0);
    float slv[4] = {sl.x, sl.y, sl.z, sl.w};
    float outv[4];
    #pragma unroll
    for (int p = 0; p < 4; p++){
        float G  = padp[p] ? 0.f : (accG[p] + gb2v);
        float Hb = padp[p] ? 0.f : (accA[p] + ab2v);
        int m = m0 + p;
        float ddg = (m == n) ? dv[b*512 + n] : 0.f;
        outv[p] = (slv[p] + sg*G + sa*Hb + ddg) * ls;
    }
    *(float4*)(S + (size_t)flat0) = make_float4(outv[0], outv[1], outv[2], outv[3]);
}

extern "C" void kernel_launch(void* const* d_in, const int* in_sizes, int n_in,
                              void* d_out, int out_size, void* d_ws, size_t ws_size,
                              hipStream_t stream){
    const float* feats = (const float*)d_in[0];
    const float* xy    = (const float*)d_in[1];
    const float* Wq    = (const float*)d_in[2];
    const float* Wk    = (const float*)d_in[3];
    const float* Wpi   = (const float*)d_in[4];
    const float* bpi   = (const float*)d_in[5];
    const float* Wpj   = (const float*)d_in[6];
    const float* bpj   = (const float*)d_in[7];
    const float* gW1   = (const float*)d_in[8];
    const float* gb1   = (const float*)d_in[9];
    const float* gW2   = (const float*)d_in[10];
    const float* gb2   = (const float*)d_in[11];
    const float* aW1   = (const float*)d_in[12];
    const float* ab1   = (const float*)d_in[13];
    const float* aW2   = (const float*)d_in[14];
    const float* ab2   = (const float*)d_in[15];
    const float* dW    = (const float*)d_in[16];
    const float* db    = (const float*)d_in[17];
    const float* a_pair= (const float*)d_in[18];
    const float* a_geom= (const float*)d_in[19];
    const float* a_ang = (const float*)d_in[20];
    const float* lsc   = (const float*)d_in[21];

    float* S  = (float*)d_out;
    float* ws = (float*)d_ws;
    float* x    = ws;               // 4096*256  = 1,048,576
    float* Wcat = x + 1048576;      // 256*448   =   114,688
    float* bcat = Wcat + 114688;    //               448
    float* U    = bcat + 448;       // 4096*208  =   851,968
    float* V    = U + 851968;       // 4096*208  =   851,968
    float* dv   = V + 851968;       //               4,096
    // total ~11.5 MB of d_ws

    k_x    <<<4096, 256, 0, stream>>>(feats, x);
    k_pack <<<448, 256, 0, stream>>>(Wq, Wk, Wpi, bpi, Wpj, bpj, dW, db, a_pair, Wcat, bcat);
    k_uv   <<<dim3(7,64), 256, 0, stream>>>(x, Wcat, bcat, U, V, dv);
    k_gemm <<<dim3(8,8,8), 256, 0, stream>>>(U, V, S);
    k_pairs<<<2048, 256, 0, stream>>>(xy, gW1, gb1, gW2, gb2, aW1, ab1, aW2, ab2,
                                      dv, a_geom, a_ang, lsc, S);
}

// Round 5
// 100.281 us; speedup vs baseline: 1.0813x; 1.0813x over previous
//
#include <hip/hip_runtime.h>
#include <math.h>

// ScoreNet: B=8, NV=512, C=256, H=6, R=32, PAIR_H=16, RBF_K=8
// R4 change: k_pairs stall-elimination —
//   * weights packed into 16B-aligned LDS rows (gws[32][16], aws[16][8])
//   * h-loops unrolled so weight loads pipeline ahead of the FMAs
//   * 8 expf/pair -> 2 expf/pair via phi_k = e0 * E^k * exp(-k^2/2)
//   * __launch_bounds__(256,4) to pin VGPR<=128 (4 waves/SIMD)
// Other kernels unchanged.

#define NCAT 448
#define NCAT_REAL 417
#define UCOLS 208

__device__ __forceinline__ float sigmoidf_(float x){ return 1.0f/(1.0f + __expf(-x)); }

__global__ __launch_bounds__(256) void k_x(const float* __restrict__ feats, float* __restrict__ x){
    int row = blockIdx.x;            // b*512 + n
    int b = row >> 9, n = row & 511;
    size_t base = ((size_t)(b*1025 + 1 + 2*n))*256 + threadIdx.x;
    x[(size_t)row*256 + threadIdx.x] = 0.5f*(feats[base] + feats[base+256]);
}

__global__ __launch_bounds__(256) void k_pack(const float* __restrict__ Wq, const float* __restrict__ Wk,
        const float* __restrict__ Wpi, const float* __restrict__ bpi,
        const float* __restrict__ Wpj, const float* __restrict__ bpj,
        const float* __restrict__ dW, const float* __restrict__ db,
        const float* __restrict__ a_pair,
        float* __restrict__ Wcat, float* __restrict__ bcat){
    int idx = blockIdx.x*256 + threadIdx.x;   // 0 .. 114687 (= 256*448)
    int c = idx / NCAT;
    int col = idx - c*NCAT;
    float sp = 1.5f * sigmoidf_(a_pair[0]);
    const float invSqrtR = 0.17677669529663687f; // 1/sqrt(32)
    float v;
    if      (col < 192) v = Wq[c*192 + col] * invSqrtR;
    else if (col < 208) v = sp * Wpi[c*16 + (col-192)];
    else if (col < 400) v = Wk[c*192 + (col-208)];
    else if (col < 416) v = Wpj[c*16 + (col-400)];
    else if (col == 416) v = dW[c];
    else v = 0.f;
    Wcat[idx] = v;
    if (idx < NCAT){
        float bv = 0.f;
        if      (idx >= 192 && idx < 208) bv = sp * bpi[idx-192];
        else if (idx >= 400 && idx < 416) bv = bpj[idx-400];
        else if (idx == 416)              bv = db[0];
        bcat[idx] = bv;
    }
}

// x[4096][256] @ Wcat[256][448] with routing epilogue -> U, V, dv
__global__ __launch_bounds__(256) void k_uv(const float* __restrict__ x, const float* __restrict__ Wcat,
        const float* __restrict__ bcat, float* __restrict__ U, float* __restrict__ V, float* __restrict__ dv){
    __shared__ float Xs[16][68];
    __shared__ float Ws[16][68];
    int tid = threadIdx.x;
    int c0 = blockIdx.x*64, r0 = blockIdx.y*64;
    int tx = tid & 15, ty = tid >> 4;
    int lr = tid >> 2, lk = (tid & 3)*4;     // x-tile loader
    int lc = tid & 63, lkw = tid >> 6;       // W-tile loader
    float acc[4][4] = {};
    for (int k0 = 0; k0 < 256; k0 += 16){
        float4 xa = *(const float4*)(x + (size_t)(r0+lr)*256 + k0 + lk);
        float wv[4];
        #pragma unroll
        for (int j = 0; j < 4; j++) wv[j] = Wcat[(size_t)(k0 + lkw + j*4)*NCAT + c0 + lc];
        __syncthreads();
        Xs[lk+0][lr]=xa.x; Xs[lk+1][lr]=xa.y; Xs[lk+2][lr]=xa.z; Xs[lk+3][lr]=xa.w;
        #pragma unroll
        for (int j = 0; j < 4; j++) Ws[lkw + j*4][lc] = wv[j];
        __syncthreads();
        #pragma unroll
        for (int k = 0; k < 16; k++){
            float4 a  = *(const float4*)&Xs[k][ty*4];
            float4 bb = *(const float4*)&Ws[k][tx*4];
            float av[4] = {a.x,a.y,a.z,a.w};
            float bv[4] = {bb.x,bb.y,bb.z,bb.w};
            #pragma unroll
            for (int i = 0; i < 4; i++)
                #pragma unroll
                for (int j = 0; j < 4; j++)
                    acc[i][j] += av[i]*bv[j];
        }
    }
    #pragma unroll
    for (int i = 0; i < 4; i++){
        int row = r0 + ty*4 + i;
        #pragma unroll
        for (int j = 0; j < 4; j++){
            int col = c0 + tx*4 + j;
            if (col >= NCAT_REAL) continue;
            float v = acc[i][j] + bcat[col];
            if (col < 208){
                if (col >= 192) v = fmaxf(v, 0.f);
                U[(size_t)row*UCOLS + col] = v;
            } else if (col < 416){
                int cc = col - 208;
                if (cc >= 192) v = fmaxf(v, 0.f);
                V[(size_t)row*UCOLS + cc] = v;
            } else {
                dv[row] = v;
            }
        }
    }
}

// S_lin[b][n][m] = sum_k U[b,n,k]*V[b,m,k]
__global__ __launch_bounds__(256) void k_gemm(const float* __restrict__ U, const float* __restrict__ V,
                                              float* __restrict__ S){
    __shared__ float Us[16][68];
    __shared__ float Vs[16][68];
    int tid = threadIdx.x;
    int b = blockIdx.z;
    int m0 = blockIdx.x*64, n0 = blockIdx.y*64;
    const float* Ub = U + ((size_t)b*512 + n0)*UCOLS;
    const float* Vb = V + ((size_t)b*512 + m0)*UCOLS;
    int tx = tid & 15, ty = tid >> 4;
    int lr = tid >> 2, lk = (tid & 3)*4;
    float acc[4][4] = {};
    for (int k0 = 0; k0 < 208; k0 += 16){
        float4 ua = *(const float4*)(Ub + (size_t)lr*UCOLS + k0 + lk);
        float4 va = *(const float4*)(Vb + (size_t)lr*UCOLS + k0 + lk);
        __syncthreads();
        Us[lk+0][lr]=ua.x; Us[lk+1][lr]=ua.y; Us[lk+2][lr]=ua.z; Us[lk+3][lr]=ua.w;
        Vs[lk+0][lr]=va.x; Vs[lk+1][lr]=va.y; Vs[lk+2][lr]=va.z; Vs[lk+3][lr]=va.w;
        __syncthreads();
        #pragma unroll
        for (int k = 0; k < 16; k++){
            float4 a  = *(const float4*)&Us[k][ty*4];
            float4 bb = *(const float4*)&Vs[k][tx*4];
            float av[4] = {a.x,a.y,a.z,a.w};
            float bv[4] = {bb.x,bb.y,bb.z,bb.w};
            #pragma unroll
            for (int i = 0; i < 4; i++)
                #pragma unroll
                for (int j = 0; j < 4; j++)
                    acc[i][j] += av[i]*bv[j];
        }
    }
    float* Sp = S + ((size_t)b*512 + n0 + ty*4)*512 + m0 + tx*4;
    #pragma unroll
    for (int i = 0; i < 4; i++)
        *(float4*)(Sp + (size_t)i*512) = make_float4(acc[i][0], acc[i][1], acc[i][2], acc[i][3]);
}

// per-pair geom + angle MLPs; in-place on S (d_out)
// gws[h][0:16] = [w_dy, w_dx, w_phi0..7, w_c1, w_s1, bias, w2, 0, 0]  (64B rows)
// aws[h][0:8]  = [w_c1, w_s1, w_c2, w_s2, w_c4, w_s4, bias, w2]      (32B rows)
__global__ __launch_bounds__(256, 4) void k_pairs(const float* __restrict__ xy,
        const float* __restrict__ gW1, const float* __restrict__ gb1,
        const float* __restrict__ gW2, const float* __restrict__ gb2,
        const float* __restrict__ aW1, const float* __restrict__ ab1,
        const float* __restrict__ aW2, const float* __restrict__ ab2,
        const float* __restrict__ dv,
        const float* __restrict__ a_geom, const float* __restrict__ a_ang,
        const float* __restrict__ lsc,
        float* __restrict__ S){
    __shared__ __attribute__((aligned(16))) float gws[32][16];
    __shared__ __attribute__((aligned(16))) float aws[16][8];
    int tid = threadIdx.x;
    for (int i = tid; i < 512; i += 256){
        int h = i >> 4, c = i & 15;
        float v = 0.f;
        if      (c < 12) v = gW1[c*32 + h];
        else if (c == 12) v = gb1[h];
        else if (c == 13) v = gW2[h];
        gws[h][c] = v;
    }
    if (tid < 128){
        int h = tid >> 3, c = tid & 7;
        float v;
        if      (c < 6)  v = aW1[c*16 + h];
        else if (c == 6) v = ab1[h];
        else             v = aW2[h];
        aws[h][c] = v;
    }
    __syncthreads();

    float sg = 1.5f*sigmoidf_(a_geom[0]);
    float sa = 1.5f*sigmoidf_(a_ang[0]);
    float ls = 0.5f + 2.5f*sigmoidf_(lsc[0]);
    float cb = sg*gb2[0] + sa*ab2[0];

    int flat0 = (blockIdx.x*256 + tid)*4;
    int m0 = flat0 & 511;
    int n  = (flat0 >> 9) & 511;
    int b  = flat0 >> 18;
    const float* xyb = xy + (size_t)b*1024;
    float2 pn = *(const float2*)(xyb + 2*n);
    float yn = pn.x, xn = pn.y;
    bool padn = (fabsf(yn) < 1e-9f) && (fabsf(xn) < 1e-9f);
    float4 q0 = *(const float4*)(xyb + 2*m0);
    float4 q1 = *(const float4*)(xyb + 2*m0 + 4);
    float ym[4] = {q0.x, q0.z, q1.x, q1.z};
    float xm[4] = {q0.y, q0.w, q1.y, q1.w};

    const float GAMMA = 12.2499985f;    // 1/(2*spacing^2 + 1e-8)
    const float TWOGD = 4.9497469f;     // 2*GAMMA*spacing

    float dy[4], dx[4], c1[4], s1[4], r2e[4], msk[4];
    float c2v[4], s2v[4], c4v[4], s4v[4];
    #pragma unroll
    for (int p = 0; p < 4; p++){
        float dyp = yn - ym[p], dxp = xn - xm[p];
        dy[p] = dyp; dx[p] = dxp;
        bool padm = (fabsf(ym[p]) < 1e-9f) && (fabsf(xm[p]) < 1e-9f);
        msk[p] = (padn || padm) ? 0.f : 1.f;
        float r2 = dyp*dyp + dxp*dxp;
        r2e[p] = r2 + 1e-8f;
        float c, s;
        if (r2 > 0.f){ float inv = rsqrtf(r2); c = dxp*inv; s = dyp*inv; }
        else { c = 1.f; s = 0.f; }   // atan2(0,0) = 0
        c1[p] = c; s1[p] = s;
        float cc2 = c*c - s*s, ss2 = 2.f*c*s;
        c2v[p] = cc2; s2v[p] = ss2;
        c4v[p] = cc2*cc2 - ss2*ss2; s4v[p] = 2.f*cc2*ss2;
    }

    // angle MLP first (frees c2..s4 before phi materialization)
    float accA[4] = {0,0,0,0};
    #pragma unroll 4
    for (int h = 0; h < 16; h++){
        float4 a0 = *(const float4*)&aws[h][0];
        float4 a1 = *(const float4*)&aws[h][4];
        #pragma unroll
        for (int p = 0; p < 4; p++){
            float s = a1.z + c1[p]*a0.x + s1[p]*a0.y + c2v[p]*a0.z + s2v[p]*a0.w
                    + c4v[p]*a1.x + s4v[p]*a1.y;
            accA[p] = fmaf(a1.w, fmaxf(s, 0.f), accA[p]);
        }
    }

    // RBF via recurrence: phi_k = e0 * E^k * exp(-k^2/2); 2 expf per pair
    float ph[4][8];
    #pragma unroll
    for (int p = 0; p < 4; p++){
        float re2 = r2e[p];
        float re  = sqrtf(re2);
        float e0  = __expf(-GAMMA*re2);
        float E   = __expf(TWOGD*re);
        float u = e0;
        ph[p][0] = u;
        u *= E; ph[p][1] = 0.60653066f*u;
        u *= E; ph[p][2] = 0.13533528f*u;
        u *= E; ph[p][3] = 0.011108997f*u;
        u *= E; ph[p][4] = 3.3546263e-4f*u;
        u *= E; ph[p][5] = 3.7266532e-6f*u;
        u *= E; ph[p][6] = 1.5229979e-8f*u;
        u *= E; ph[p][7] = 2.2897348e-11f*u;
    }

    float accG[4] = {0,0,0,0};
    #pragma unroll 2
    for (int h = 0; h < 32; h++){
        float4 w0 = *(const float4*)&gws[h][0];
        float4 w1 = *(const float4*)&gws[h][4];
        float4 w2 = *(const float4*)&gws[h][8];
        float4 w3 = *(const float4*)&gws[h][12];   // x=bias, y=w2out
        #pragma unroll
        for (int p = 0; p < 4; p++){
            float s = w3.x + dy[p]*w0.x + dx[p]*w0.y
                    + ph[p][0]*w0.z + ph[p][1]*w0.w
                    + ph[p][2]*w1.x + ph[p][3]*w1.y + ph[p][4]*w1.z + ph[p][5]*w1.w
                    + ph[p][6]*w2.x + ph[p][7]*w2.y + c1[p]*w2.z + s1[p]*w2.w;
            accG[p] = fmaf(w3.y, fmaxf(s, 0.f), accG[p]);
        }
    }

    float4 sl = *(const float4*)(S + (size_t)flat0);
    float slv[4] = {sl.x, sl.y, sl.z, sl.w};
    float dvn = dv[b*512 + n];
    float outv[4];
    #pragma unroll
    for (int p = 0; p < 4; p++){
        float add = msk[p] * (sg*accG[p] + sa*accA[p] + cb);
        float ddg = (m0 + p == n) ? dvn : 0.f;
        outv[p] = (slv[p] + add + ddg) * ls;
    }
    *(float4*)(S + (size_t)flat0) = make_float4(outv[0], outv[1], outv[2], outv[3]);
}

extern "C" void kernel_launch(void* const* d_in, const int* in_sizes, int n_in,
                              void* d_out, int out_size, void* d_ws, size_t ws_size,
                              hipStream_t stream){
    const float* feats = (const float*)d_in[0];
    const float* xy    = (const float*)d_in[1];
    const float* Wq    = (const float*)d_in[2];
    const float* Wk    = (const float*)d_in[3];
    const float* Wpi   = (const float*)d_in[4];
    const float* bpi   = (const float*)d_in[5];
    const float* Wpj   = (const float*)d_in[6];
    const float* bpj   = (const float*)d_in[7];
    const float* gW1   = (const float*)d_in[8];
    const float* gb1   = (const float*)d_in[9];
    const float* gW2   = (const float*)d_in[10];
    const float* gb2   = (const float*)d_in[11];
    const float* aW1   = (const float*)d_in[12];
    const float* ab1   = (const float*)d_in[13];
    const float* aW2   = (const float*)d_in[14];
    const float* ab2   = (const float*)d_in[15];
    const float* dW    = (const float*)d_in[16];
    const float* db    = (const float*)d_in[17];
    const float* a_pair= (const float*)d_in[18];
    const float* a_geom= (const float*)d_in[19];
    const float* a_ang = (const float*)d_in[20];
    const float* lsc   = (const float*)d_in[21];

    float* S  = (float*)d_out;
    float* ws = (float*)d_ws;
    float* x    = ws;               // 4096*256  = 1,048,576
    float* Wcat = x + 1048576;      // 256*448   =   114,688
    float* bcat = Wcat + 114688;    //               448
    float* U    = bcat + 448;       // 4096*208  =   851,968
    float* V    = U + 851968;       // 4096*208  =   851,968
    float* dv   = V + 851968;       //               4,096
    // total ~11.5 MB of d_ws

    k_x    <<<4096, 256, 0, stream>>>(feats, x);
    k_pack <<<448, 256, 0, stream>>>(Wq, Wk, Wpi, bpi, Wpj, bpj, dW, db, a_pair, Wcat, bcat);
    k_uv   <<<dim3(7,64), 256, 0, stream>>>(x, Wcat, bcat, U, V, dv);
    k_gemm <<<dim3(8,8,8), 256, 0, stream>>>(U, V, S);
    k_pairs<<<2048, 256, 0, stream>>>(xy, gW1, gb1, gW2, gb2, aW1, ab1, aW2, ab2,
                                      dv, a_geom, a_ang, lsc, S);
}

// Round 7
// 79.851 us; speedup vs baseline: 1.3579x; 1.2559x over previous
//
#include <hip/hip_runtime.h>
#include <math.h>

// ScoreNet: B=8, NV=512, C=256, H=6, R=32, PAIR_H=16, RBF_K=8
// R6 fix: R5's MFMA k_pairs had a shfl source-evaluation bug
//   (__shfl(hf ? pk4 : pk0, src) selects in the SOURCE lane).
//   Now shuffle both halves, select with reader's hf afterwards.
// Other kernels unchanged.

#define NCAT 448
#define NCAT_REAL 417
#define UCOLS 208

typedef __attribute__((ext_vector_type(8)))  short short8;
typedef __attribute__((ext_vector_type(16))) float f32x16;
typedef __attribute__((ext_vector_type(4)))  int   int4v;

__device__ __forceinline__ float sigmoidf_(float x){ return 1.0f/(1.0f + __expf(-x)); }
__device__ __forceinline__ unsigned f2bf(float x){
    unsigned u = __builtin_bit_cast(unsigned, x);
    return (u + 0x7fffu + ((u>>16)&1u)) >> 16;       // RNE f32->bf16
}
__device__ __forceinline__ unsigned pack2(float a, float b){
    return f2bf(a) | (f2bf(b)<<16);
}
__device__ __forceinline__ f32x16 zero16(){
    f32x16 z;
    #pragma unroll
    for (int i = 0; i < 16; i++) z[i] = 0.f;
    return z;
}

__global__ __launch_bounds__(256) void k_x(const float* __restrict__ feats, float* __restrict__ x){
    int row = blockIdx.x;            // b*512 + n
    int b = row >> 9, n = row & 511;
    size_t base = ((size_t)(b*1025 + 1 + 2*n))*256 + threadIdx.x;
    x[(size_t)row*256 + threadIdx.x] = 0.5f*(feats[base] + feats[base+256]);
}

__global__ __launch_bounds__(256) void k_pack(const float* __restrict__ Wq, const float* __restrict__ Wk,
        const float* __restrict__ Wpi, const float* __restrict__ bpi,
        const float* __restrict__ Wpj, const float* __restrict__ bpj,
        const float* __restrict__ dW, const float* __restrict__ db,
        const float* __restrict__ a_pair,
        float* __restrict__ Wcat, float* __restrict__ bcat){
    int idx = blockIdx.x*256 + threadIdx.x;   // 0 .. 114687 (= 256*448)
    int c = idx / NCAT;
    int col = idx - c*NCAT;
    float sp = 1.5f * sigmoidf_(a_pair[0]);
    const float invSqrtR = 0.17677669529663687f; // 1/sqrt(32)
    float v;
    if      (col < 192) v = Wq[c*192 + col] * invSqrtR;
    else if (col < 208) v = sp * Wpi[c*16 + (col-192)];
    else if (col < 400) v = Wk[c*192 + (col-208)];
    else if (col < 416) v = Wpj[c*16 + (col-400)];
    else if (col == 416) v = dW[c];
    else v = 0.f;
    Wcat[idx] = v;
    if (idx < NCAT){
        float bv = 0.f;
        if      (idx >= 192 && idx < 208) bv = sp * bpi[idx-192];
        else if (idx >= 400 && idx < 416) bv = bpj[idx-400];
        else if (idx == 416)              bv = db[0];
        bcat[idx] = bv;
    }
}

// x[4096][256] @ Wcat[256][448] with routing epilogue -> U, V, dv
__global__ __launch_bounds__(256) void k_uv(const float* __restrict__ x, const float* __restrict__ Wcat,
        const float* __restrict__ bcat, float* __restrict__ U, float* __restrict__ V, float* __restrict__ dv){
    __shared__ float Xs[16][68];
    __shared__ float Ws[16][68];
    int tid = threadIdx.x;
    int c0 = blockIdx.x*64, r0 = blockIdx.y*64;
    int tx = tid & 15, ty = tid >> 4;
    int lr = tid >> 2, lk = (tid & 3)*4;     // x-tile loader
    int lc = tid & 63, lkw = tid >> 6;       // W-tile loader
    float acc[4][4] = {};
    for (int k0 = 0; k0 < 256; k0 += 16){
        float4 xa = *(const float4*)(x + (size_t)(r0+lr)*256 + k0 + lk);
        float wv[4];
        #pragma unroll
        for (int j = 0; j < 4; j++) wv[j] = Wcat[(size_t)(k0 + lkw + j*4)*NCAT + c0 + lc];
        __syncthreads();
        Xs[lk+0][lr]=xa.x; Xs[lk+1][lr]=xa.y; Xs[lk+2][lr]=xa.z; Xs[lk+3][lr]=xa.w;
        #pragma unroll
        for (int j = 0; j < 4; j++) Ws[lkw + j*4][lc] = wv[j];
        __syncthreads();
        #pragma unroll
        for (int k = 0; k < 16; k++){
            float4 a  = *(const float4*)&Xs[k][ty*4];
            float4 bb = *(const float4*)&Ws[k][tx*4];
            float av[4] = {a.x,a.y,a.z,a.w};
            float bv[4] = {bb.x,bb.y,bb.z,bb.w};
            #pragma unroll
            for (int i = 0; i < 4; i++)
                #pragma unroll
                for (int j = 0; j < 4; j++)
                    acc[i][j] += av[i]*bv[j];
        }
    }
    #pragma unroll
    for (int i = 0; i < 4; i++){
        int row = r0 + ty*4 + i;
        #pragma unroll
        for (int j = 0; j < 4; j++){
            int col = c0 + tx*4 + j;
            if (col >= NCAT_REAL) continue;
            float v = acc[i][j] + bcat[col];
            if (col < 208){
                if (col >= 192) v = fmaxf(v, 0.f);
                U[(size_t)row*UCOLS + col] = v;
            } else if (col < 416){
                int cc = col - 208;
                if (cc >= 192) v = fmaxf(v, 0.f);
                V[(size_t)row*UCOLS + cc] = v;
            } else {
                dv[row] = v;
            }
        }
    }
}

// S_lin[b][n][m] = sum_k U[b,n,k]*V[b,m,k]
__global__ __launch_bounds__(256) void k_gemm(const float* __restrict__ U, const float* __restrict__ V,
                                              float* __restrict__ S){
    __shared__ float Us[16][68];
    __shared__ float Vs[16][68];
    int tid = threadIdx.x;
    int b = blockIdx.z;
    int m0 = blockIdx.x*64, n0 = blockIdx.y*64;
    const float* Ub = U + ((size_t)b*512 + n0)*UCOLS;
    const float* Vb = V + ((size_t)b*512 + m0)*UCOLS;
    int tx = tid & 15, ty = tid >> 4;
    int lr = tid >> 2, lk = (tid & 3)*4;
    float acc[4][4] = {};
    for (int k0 = 0; k0 < 208; k0 += 16){
        float4 ua = *(const float4*)(Ub + (size_t)lr*UCOLS + k0 + lk);
        float4 va = *(const float4*)(Vb + (size_t)lr*UCOLS + k0 + lk);
        __syncthreads();
        Us[lk+0][lr]=ua.x; Us[lk+1][lr]=ua.y; Us[lk+2][lr]=ua.z; Us[lk+3][lr]=ua.w;
        Vs[lk+0][lr]=va.x; Vs[lk+1][lr]=va.y; Vs[lk+2][lr]=va.z; Vs[lk+3][lr]=va.w;
        __syncthreads();
        #pragma unroll
        for (int k = 0; k < 16; k++){
            float4 a  = *(const float4*)&Us[k][ty*4];
            float4 bb = *(const float4*)&Vs[k][tx*4];
            float av[4] = {a.x,a.y,a.z,a.w};
            float bv[4] = {bb.x,bb.y,bb.z,bb.w};
            #pragma unroll
            for (int i = 0; i < 4; i++)
                #pragma unroll
                for (int j = 0; j < 4; j++)
                    acc[i][j] += av[i]*bv[j];
        }
    }
    float* Sp = S + ((size_t)b*512 + n0 + ty*4)*512 + m0 + tx*4;
    #pragma unroll
    for (int i = 0; i < 4; i++)
        *(float4*)(Sp + (size_t)i*512) = make_float4(acc[i][0], acc[i][1], acc[i][2], acc[i][3]);
}

// per-pair geom + angle MLPs via MFMA; in-place RMW on S (d_out)
// features f0..f15 = [dy,dx,phi0..7,c1,s1,c2,s2,c4,s4]  (K=16, no pad)
// A (geom) = gW1^T rows=hidden(32), A (angle) = aW1^T rows 0..15, rows 16..31 zero
// B = F^T cols=pairs(32), built by shuffles from owner lanes
// D[h][pair]: col=lane&31, row=(r&3)+8*(r>>2)+4*(lane>>5)   [m74/m101]
__global__ __launch_bounds__(256, 3) void k_pairs(const float* __restrict__ xy,
        const float* __restrict__ gW1, const float* __restrict__ gb1,
        const float* __restrict__ gW2, const float* __restrict__ gb2,
        const float* __restrict__ aW1, const float* __restrict__ ab1,
        const float* __restrict__ aW2, const float* __restrict__ ab2,
        const float* __restrict__ dv,
        const float* __restrict__ a_geom, const float* __restrict__ a_ang,
        const float* __restrict__ lsc,
        float* __restrict__ S){
    int tid  = threadIdx.x;
    int lane = tid & 63;
    int hf   = lane >> 5;     // k-half for A/B frags; row-half for C/D
    int l31  = lane & 31;

    float sg = 1.5f*sigmoidf_(a_geom[0]);
    float sa = 1.5f*sigmoidf_(a_ang[0]);
    float ls = 0.5f + 2.5f*sigmoidf_(lsc[0]);

    // A-fragments (weights): lane holds A[row=l31][k=hf*8+j]
    short8 wg, wa;
    #pragma unroll
    for (int j = 0; j < 8; j++){
        int f = hf*8 + j;
        float vg = (f < 12) ? gW1[f*32 + l31] : 0.f;
        float va = (f >= 10 && l31 < 16) ? aW1[(f-10)*16 + l31] : 0.f;
        wg[j] = (short)f2bf(vg);
        wa[j] = (short)f2bf(va);
    }

    // per-reg tables: h = (r&3) + 8*(r>>2) + 4*hf  (C/D row of reg r)
    float nbg[16], g2g[16], nba[16], g2a[16];
    float bsum = 0.f;
    #pragma unroll
    for (int r = 0; r < 16; r++){
        int h = (r&3) + 8*(r>>2) + 4*hf;
        float bg  = gb1[h];
        float wg2 = sg*gW2[h];
        nbg[r] = -bg; g2g[r] = wg2; bsum += bg*wg2;
        if (h < 16){
            float ba  = ab1[h];
            float wa2 = sa*aW2[h];
            nba[r] = -ba; g2a[r] = wa2; bsum += ba*wa2;
        } else { nba[r] = 0.f; g2a[r] = 0.f; }
    }
    bsum += __shfl_xor(bsum, 32);
    float cb = sg*gb2[0] + sa*ab2[0] + bsum;

    const float GAMMA = 12.2499985f;    // 1/(2*spacing^2 + 1e-8)
    const float TWOGD = 4.9497469f;     // 2*GAMMA*spacing

    int wave_g = blockIdx.x*4 + (tid >> 6);     // 768*4 = 3072 waves
    for (int c = wave_g; c < 32768; c += 3072){
        int flat = c*64 + lane;                 // this lane's own pair
        int m = flat & 511, n = (flat >> 9) & 511, b = flat >> 18;
        const float* xyb = xy + (size_t)b*1024;
        float yn = xyb[2*n], xn = xyb[2*n+1];
        float2 pm = *(const float2*)(xyb + 2*m);
        float ym = pm.x, xm = pm.y;
        bool padn = (fabsf(yn) < 1e-9f) && (fabsf(xn) < 1e-9f);
        bool padm = (fabsf(ym) < 1e-9f) && (fabsf(xm) < 1e-9f);
        float msk = (padn || padm) ? 0.f : 1.f;

        float dy = yn - ym, dx = xn - xm;
        float r2 = dy*dy + dx*dx;
        float re = sqrtf(r2 + 1e-8f);
        float c1, s1;
        if (r2 > 0.f){ float inv = rsqrtf(r2); c1 = dx*inv; s1 = dy*inv; }
        else { c1 = 1.f; s1 = 0.f; }   // atan2(0,0)=0
        float c2 = c1*c1 - s1*s1, s2 = 2.f*c1*s1;
        float c4 = c2*c2 - s2*s2, s4 = 2.f*c2*s2;

        // RBF recurrence: phi_k = e0 * E^k * exp(-k^2/2)
        float e0 = __expf(-GAMMA*(r2 + 1e-8f));
        float E  = __expf(TWOGD*re);
        float u  = e0;
        float p0 = u;
        u *= E; float p1 = 0.60653066f*u;
        u *= E; float p2 = 0.13533528f*u;
        u *= E; float p3 = 0.011108997f*u;
        u *= E; float p4 = 3.3546263e-4f*u;
        u *= E; float p5 = 3.7266532e-6f*u;
        u *= E; float p6 = 1.5229979e-8f*u;
        u *= E; float p7 = 2.2897348e-11f*u;

        unsigned pk0 = pack2(dy, dx), pk1 = pack2(p0, p1), pk2 = pack2(p2, p3), pk3 = pack2(p4, p5);
        unsigned pk4 = pack2(p6, p7), pk5 = pack2(c1, s1), pk6 = pack2(c2, s2), pk7 = pack2(c4, s4);

        float diagv = 0.f;
        if (m == n) diagv = dv[b*512 + n];

        #pragma unroll
        for (int g = 0; g < 2; g++){
            int src = g*32 + l31;   // owner lane of pair column l31 in group g
            // shuffle BOTH halves; select with reader's hf AFTER the shuffle
            int t0 = __shfl((int)pk0, src);
            int t1 = __shfl((int)pk1, src);
            int t2 = __shfl((int)pk2, src);
            int t3 = __shfl((int)pk3, src);
            int t4 = __shfl((int)pk4, src);
            int t5 = __shfl((int)pk5, src);
            int t6 = __shfl((int)pk6, src);
            int t7 = __shfl((int)pk7, src);
            int q0 = hf ? t4 : t0;
            int q1 = hf ? t5 : t1;
            int q2 = hf ? t6 : t2;
            int q3 = hf ? t7 : t3;
            int4v iv = {q0, q1, q2, q3};
            short8 bfrag = __builtin_bit_cast(short8, iv);

            f32x16 z  = zero16();
            f32x16 dg = __builtin_amdgcn_mfma_f32_32x32x16_bf16(wg, bfrag, z, 0, 0, 0);
            f32x16 da = __builtin_amdgcn_mfma_f32_32x32x16_bf16(wa, bfrag, z, 0, 0, 0);

            // layer 2: relu(x+b)*w2 = (max(x,-b)+b)*w2 ; bias*w2 folded into cb
            float acc = 0.f;
            #pragma unroll
            for (int r = 0; r < 16; r++){
                acc += fmaxf(dg[r], nbg[r]) * g2g[r];
                acc += fmaxf(da[r], nba[r]) * g2a[r];
            }
            acc += __shfl_xor(acc, 32);   // other row-half

            if (hf == g){   // writer == owner lane (pair == flat)
                float sv = S[(size_t)flat];
                S[(size_t)flat] = (sv + msk*(acc + cb) + diagv) * ls;
            }
        }
    }
}

extern "C" void kernel_launch(void* const* d_in, const int* in_sizes, int n_in,
                              void* d_out, int out_size, void* d_ws, size_t ws_size,
                              hipStream_t stream){
    const float* feats = (const float*)d_in[0];
    const float* xy    = (const float*)d_in[1];
    const float* Wq    = (const float*)d_in[2];
    const float* Wk    = (const float*)d_in[3];
    const float* Wpi   = (const float*)d_in[4];
    const float* bpi   = (const float*)d_in[5];
    const float* Wpj   = (const float*)d_in[6];
    const float* bpj   = (const float*)d_in[7];
    const float* gW1   = (const float*)d_in[8];
    const float* gb1   = (const float*)d_in[9];
    const float* gW2   = (const float*)d_in[10];
    const float* gb2   = (const float*)d_in[11];
    const float* aW1   = (const float*)d_in[12];
    const float* ab1   = (const float*)d_in[13];
    const float* aW2   = (const float*)d_in[14];
    const float* ab2   = (const float*)d_in[15];
    const float* dW    = (const float*)d_in[16];
    const float* db    = (const float*)d_in[17];
    const float* a_pair= (const float*)d_in[18];
    const float* a_geom= (const float*)d_in[19];
    const float* a_ang = (const float*)d_in[20];
    const float* lsc   = (const float*)d_in[21];

    float* S  = (float*)d_out;
    float* ws = (float*)d_ws;
    float* x    = ws;               // 4096*256  = 1,048,576
    float* Wcat = x + 1048576;      // 256*448   =   114,688
    float* bcat = Wcat + 114688;    //               448
    float* U    = bcat + 448;       // 4096*208  =   851,968
    float* V    = U + 851968;       // 4096*208  =   851,968
    float* dv   = V + 851968;       //               4,096
    // total ~11.5 MB of d_ws

    k_x    <<<4096, 256, 0, stream>>>(feats, x);
    k_pack <<<448, 256, 0, stream>>>(Wq, Wk, Wpi, bpi, Wpj, bpj, dW, db, a_pair, Wcat, bcat);
    k_uv   <<<dim3(7,64), 256, 0, stream>>>(x, Wcat, bcat, U, V, dv);
    k_gemm <<<dim3(8,8,8), 256, 0, stream>>>(U, V, S);
    k_pairs<<<768, 256, 0, stream>>>(xy, gW1, gb1, gW2, gb2, aW1, ab1, aW2, ab2,
                                     dv, a_geom, a_ang, lsc, S);
}

// Round 8
// 57.571 us; speedup vs baseline: 1.8835x; 1.3870x over previous
//
#include <hip/hip_runtime.h>
#include <math.h>

// ScoreNet: B=8, NV=512, C=256, H=6, R=32, PAIR_H=16, RBF_K=8
// R7 change: both GEMMs moved to bf16 MFMA (32x32x16), LDS-free (operand
//   panels are L2-resident; direct ushort8 gathers). k_x+k_pack merged into
//   k_prep which emits bf16 xb and transposed bf16 WT. k_uv emits bf16
//   Ub/Vb (K padded 208->224 with zeros) + f32 dv. k_pairs unchanged (R6).
// Fragment recipe verified on HW by R6's pass: A[row][hf*8+j], B[col][hf*8+j]
// (same k-map both sides => slot-permutation self-canceling), C/D row map
// (r&3)+8*(r>>2)+4*hf, col=lane&31.

#define UK 224

typedef __attribute__((ext_vector_type(8)))  short short8;
typedef __attribute__((ext_vector_type(16))) float f32x16;
typedef __attribute__((ext_vector_type(4)))  int   int4v;

__device__ __forceinline__ float sigmoidf_(float x){ return 1.0f/(1.0f + __expf(-x)); }
__device__ __forceinline__ unsigned f2bf(float x){
    unsigned u = __builtin_bit_cast(unsigned, x);
    return (u + 0x7fffu + ((u>>16)&1u)) >> 16;       // RNE f32->bf16
}
__device__ __forceinline__ unsigned pack2(float a, float b){
    return f2bf(a) | (f2bf(b)<<16);
}
__device__ __forceinline__ f32x16 zero16(){
    f32x16 z;
    #pragma unroll
    for (int i = 0; i < 16; i++) z[i] = 0.f;
    return z;
}

// merged: blocks <4096 pool feats -> bf16 xb; blocks >=4096 pack WT (transposed, bf16) + bcat
__global__ __launch_bounds__(256) void k_prep(const float* __restrict__ feats,
        const float* __restrict__ Wq, const float* __restrict__ Wk,
        const float* __restrict__ Wpi, const float* __restrict__ bpi,
        const float* __restrict__ Wpj, const float* __restrict__ bpj,
        const float* __restrict__ dW, const float* __restrict__ db,
        const float* __restrict__ a_pair,
        unsigned short* __restrict__ xb, unsigned short* __restrict__ WT,
        float* __restrict__ bcat){
    int blk = blockIdx.x, tid = threadIdx.x;
    if (blk < 4096){
        int b = blk >> 9, n = blk & 511;
        size_t base = ((size_t)(b*1025 + 1 + 2*n))*256 + tid;
        float v = 0.5f*(feats[base] + feats[base+256]);
        xb[(size_t)blk*256 + tid] = (unsigned short)f2bf(v);
    } else {
        int col = blk - 4096;    // 0..447
        int c   = tid;           // k index 0..255
        const float invSqrtR = 0.17677669529663687f; // 1/sqrt(32)
        float sp = 1.5f*sigmoidf_(a_pair[0]);
        float v;
        if      (col < 192)  v = Wq[c*192 + col]*invSqrtR;
        else if (col < 208)  v = sp*Wpi[c*16 + (col-192)];
        else if (col < 400)  v = Wk[c*192 + (col-208)];
        else if (col < 416)  v = Wpj[c*16 + (col-400)];
        else if (col == 416) v = dW[c];
        else v = 0.f;
        WT[col*256 + c] = (unsigned short)f2bf(v);
        if (tid == 0){
            float bv = 0.f;
            if      (col >= 192 && col < 208) bv = sp*bpi[col-192];
            else if (col >= 400 && col < 416) bv = bpj[col-400];
            else if (col == 416)              bv = db[0];
            bcat[col] = bv;
        }
    }
}

// xb[4096][256] @ WT^T -> routed to Ub/Vb (bf16, [4096][224], zero-padded) + dv
__global__ __launch_bounds__(256) void k_uv(const unsigned short* __restrict__ xb,
        const unsigned short* __restrict__ WT, const float* __restrict__ bcat,
        unsigned short* __restrict__ Ub, unsigned short* __restrict__ Vb,
        float* __restrict__ dv){
    int tid = threadIdx.x;
    int lane = tid & 63, l31 = lane & 31, hf = lane >> 5;
    int w = tid >> 6, wr = w >> 1, wc = w & 1;
    int c0 = blockIdx.x*64, r0 = blockIdx.y*64;
    const unsigned short* ap = xb + (size_t)(r0 + wr*32 + l31)*256 + 8*hf;
    const unsigned short* bp = WT + (size_t)(c0 + wc*32 + l31)*256 + 8*hf;
    f32x16 acc = zero16();
    #pragma unroll 4
    for (int k0 = 0; k0 < 256; k0 += 16){
        short8 a  = *(const short8*)(ap + k0);
        short8 bb = *(const short8*)(bp + k0);
        acc = __builtin_amdgcn_mfma_f32_32x32x16_bf16(a, bb, acc, 0, 0, 0);
    }
    int col = c0 + wc*32 + l31;          // uniform per lane across all 16 accs
    int rb  = r0 + wr*32 + 4*hf;
    float bc = bcat[col];
    #pragma unroll
    for (int r = 0; r < 16; r++){
        int row = rb + (r&3) + 8*(r>>2);
        float v = acc[r] + bc;
        size_t ui = (size_t)row*UK;
        if (col < 208){
            if (col >= 192) v = fmaxf(v, 0.f);        // a_i relu
            Ub[ui + col] = (unsigned short)f2bf(v);
        } else if (col < 224){
            Vb[ui + col-208] = (unsigned short)f2bf(v);
            Ub[ui + col] = 0;                          // Ub K-pad
        } else if (col < 416){
            if (col >= 400) v = fmaxf(v, 0.f);        // b_j relu
            Vb[ui + col-208] = (unsigned short)f2bf(v);
        } else if (col == 416){
            dv[row] = v;
            Vb[ui + 208] = 0;                          // Vb K-pad
        } else if (col < 432){
            Vb[ui + col-208] = 0;                      // Vb K-pad (cols 417..431 are zero-cols)
        }
        // col >= 432: dead padding, skip
    }
}

// S_lin[b][n][m] = Ub[b,n,:] . Vb[b,m,:]  (bf16 MFMA, K=224 incl. zero pad)
__global__ __launch_bounds__(256) void k_gemm(const unsigned short* __restrict__ Ub,
        const unsigned short* __restrict__ Vb, float* __restrict__ S){
    int tid = threadIdx.x;
    int lane = tid & 63, l31 = lane & 31, hf = lane >> 5;
    int w = tid >> 6, wr = w >> 1, wc = w & 1;
    int b = blockIdx.z;
    int m0 = blockIdx.x*64, n0 = blockIdx.y*64;
    const unsigned short* ap = Ub + (size_t)(b*512 + n0 + wr*32 + l31)*UK + 8*hf;
    const unsigned short* bp = Vb + (size_t)(b*512 + m0 + wc*32 + l31)*UK + 8*hf;
    f32x16 acc = zero16();
    #pragma unroll 2
    for (int k0 = 0; k0 < UK; k0 += 16){
        short8 a  = *(const short8*)(ap + k0);
        short8 bb = *(const short8*)(bp + k0);
        acc = __builtin_amdgcn_mfma_f32_32x32x16_bf16(a, bb, acc, 0, 0, 0);
    }
    int m  = m0 + wc*32 + l31;
    int nb = n0 + wr*32 + 4*hf;
    float* Sp = S + ((size_t)b*512)*512 + m;
    #pragma unroll
    for (int r = 0; r < 16; r++){
        int n = nb + (r&3) + 8*(r>>2);
        Sp[(size_t)n*512] = acc[r];
    }
}

// per-pair geom + angle MLPs via MFMA; in-place RMW on S (unchanged from R6)
__global__ __launch_bounds__(256, 3) void k_pairs(const float* __restrict__ xy,
        const float* __restrict__ gW1, const float* __restrict__ gb1,
        const float* __restrict__ gW2, const float* __restrict__ gb2,
        const float* __restrict__ aW1, const float* __restrict__ ab1,
        const float* __restrict__ aW2, const float* __restrict__ ab2,
        const float* __restrict__ dv,
        const float* __restrict__ a_geom, const float* __restrict__ a_ang,
        const float* __restrict__ lsc,
        float* __restrict__ S){
    int tid  = threadIdx.x;
    int lane = tid & 63;
    int hf   = lane >> 5;
    int l31  = lane & 31;

    float sg = 1.5f*sigmoidf_(a_geom[0]);
    float sa = 1.5f*sigmoidf_(a_ang[0]);
    float ls = 0.5f + 2.5f*sigmoidf_(lsc[0]);

    short8 wg, wa;
    #pragma unroll
    for (int j = 0; j < 8; j++){
        int f = hf*8 + j;
        float vg = (f < 12) ? gW1[f*32 + l31] : 0.f;
        float va = (f >= 10 && l31 < 16) ? aW1[(f-10)*16 + l31] : 0.f;
        wg[j] = (short)f2bf(vg);
        wa[j] = (short)f2bf(va);
    }

    float nbg[16], g2g[16], nba[16], g2a[16];
    float bsum = 0.f;
    #pragma unroll
    for (int r = 0; r < 16; r++){
        int h = (r&3) + 8*(r>>2) + 4*hf;
        float bg  = gb1[h];
        float wg2 = sg*gW2[h];
        nbg[r] = -bg; g2g[r] = wg2; bsum += bg*wg2;
        if (h < 16){
            float ba  = ab1[h];
            float wa2 = sa*aW2[h];
            nba[r] = -ba; g2a[r] = wa2; bsum += ba*wa2;
        } else { nba[r] = 0.f; g2a[r] = 0.f; }
    }
    bsum += __shfl_xor(bsum, 32);
    float cb = sg*gb2[0] + sa*ab2[0] + bsum;

    const float GAMMA = 12.2499985f;
    const float TWOGD = 4.9497469f;

    int wave_g = blockIdx.x*4 + (tid >> 6);
    for (int c = wave_g; c < 32768; c += 3072){
        int flat = c*64 + lane;
        int m = flat & 511, n = (flat >> 9) & 511, b = flat >> 18;
        const float* xyb = xy + (size_t)b*1024;
        float yn = xyb[2*n], xn = xyb[2*n+1];
        float2 pm = *(const float2*)(xyb + 2*m);
        float ym = pm.x, xm = pm.y;
        bool padn = (fabsf(yn) < 1e-9f) && (fabsf(xn) < 1e-9f);
        bool padm = (fabsf(ym) < 1e-9f) && (fabsf(xm) < 1e-9f);
        float msk = (padn || padm) ? 0.f : 1.f;

        float dy = yn - ym, dx = xn - xm;
        float r2 = dy*dy + dx*dx;
        float re = sqrtf(r2 + 1e-8f);
        float c1, s1;
        if (r2 > 0.f){ float inv = rsqrtf(r2); c1 = dx*inv; s1 = dy*inv; }
        else { c1 = 1.f; s1 = 0.f; }
        float c2 = c1*c1 - s1*s1, s2 = 2.f*c1*s1;
        float c4 = c2*c2 - s2*s2, s4 = 2.f*c2*s2;

        float e0 = __expf(-GAMMA*(r2 + 1e-8f));
        float E  = __expf(TWOGD*re);
        float u  = e0;
        float p0 = u;
        u *= E; float p1 = 0.60653066f*u;
        u *= E; float p2 = 0.13533528f*u;
        u *= E; float p3 = 0.011108997f*u;
        u *= E; float p4 = 3.3546263e-4f*u;
        u *= E; float p5 = 3.7266532e-6f*u;
        u *= E; float p6 = 1.5229979e-8f*u;
        u *= E; float p7 = 2.2897348e-11f*u;

        unsigned pk0 = pack2(dy, dx), pk1 = pack2(p0, p1), pk2 = pack2(p2, p3), pk3 = pack2(p4, p5);
        unsigned pk4 = pack2(p6, p7), pk5 = pack2(c1, s1), pk6 = pack2(c2, s2), pk7 = pack2(c4, s4);

        float diagv = 0.f;
        if (m == n) diagv = dv[b*512 + n];

        #pragma unroll
        for (int g = 0; g < 2; g++){
            int src = g*32 + l31;
            int t0 = __shfl((int)pk0, src);
            int t1 = __shfl((int)pk1, src);
            int t2 = __shfl((int)pk2, src);
            int t3 = __shfl((int)pk3, src);
            int t4 = __shfl((int)pk4, src);
            int t5 = __shfl((int)pk5, src);
            int t6 = __shfl((int)pk6, src);
            int t7 = __shfl((int)pk7, src);
            int q0 = hf ? t4 : t0;
            int q1 = hf ? t5 : t1;
            int q2 = hf ? t6 : t2;
            int q3 = hf ? t7 : t3;
            int4v iv = {q0, q1, q2, q3};
            short8 bfrag = __builtin_bit_cast(short8, iv);

            f32x16 z  = zero16();
            f32x16 dg = __builtin_amdgcn_mfma_f32_32x32x16_bf16(wg, bfrag, z, 0, 0, 0);
            f32x16 da = __builtin_amdgcn_mfma_f32_32x32x16_bf16(wa, bfrag, z, 0, 0, 0);

            float acc = 0.f;
            #pragma unroll
            for (int r = 0; r < 16; r++){
                acc += fmaxf(dg[r], nbg[r]) * g2g[r];
                acc += fmaxf(da[r], nba[r]) * g2a[r];
            }
            acc += __shfl_xor(acc, 32);

            if (hf == g){
                float sv = S[(size_t)flat];
                S[(size_t)flat] = (sv + msk*(acc + cb) + diagv) * ls;
            }
        }
    }
}

extern "C" void kernel_launch(void* const* d_in, const int* in_sizes, int n_in,
                              void* d_out, int out_size, void* d_ws, size_t ws_size,
                              hipStream_t stream){
    const float* feats = (const float*)d_in[0];
    const float* xy    = (const float*)d_in[1];
    const float* Wq    = (const float*)d_in[2];
    const float* Wk    = (const float*)d_in[3];
    const float* Wpi   = (const float*)d_in[4];
    const float* bpi   = (const float*)d_in[5];
    const float* Wpj   = (const float*)d_in[6];
    const float* bpj   = (const float*)d_in[7];
    const float* gW1   = (const float*)d_in[8];
    const float* gb1   = (const float*)d_in[9];
    const float* gW2   = (const float*)d_in[10];
    const float* gb2   = (const float*)d_in[11];
    const float* aW1   = (const float*)d_in[12];
    const float* ab1   = (const float*)d_in[13];
    const float* aW2   = (const float*)d_in[14];
    const float* ab2   = (const float*)d_in[15];
    const float* dW    = (const float*)d_in[16];
    const float* db    = (const float*)d_in[17];
    const float* a_pair= (const float*)d_in[18];
    const float* a_geom= (const float*)d_in[19];
    const float* a_ang = (const float*)d_in[20];
    const float* lsc   = (const float*)d_in[21];

    float* S = (float*)d_out;
    char* wsb = (char*)d_ws;
    unsigned short* xb = (unsigned short*)wsb;                    // 4096*256*2 = 2,097,152 B
    unsigned short* WT = (unsigned short*)(wsb + 2097152);        // 448*256*2  =   229,376 B
    unsigned short* Ub = (unsigned short*)(wsb + 2326528);        // 4096*224*2 = 1,835,008 B
    unsigned short* Vb = (unsigned short*)(wsb + 4161536);        // 1,835,008 B
    float* bcat = (float*)(wsb + 5996544);                        // 448*4
    float* dv   = (float*)(wsb + 5998336);                        // 4096*4
    // total ~6.0 MB of d_ws

    k_prep <<<4544, 256, 0, stream>>>(feats, Wq, Wk, Wpi, bpi, Wpj, bpj, dW, db, a_pair,
                                      xb, WT, bcat);
    k_uv   <<<dim3(7,64), 256, 0, stream>>>(xb, WT, bcat, Ub, Vb, dv);
    k_gemm <<<dim3(8,8,8), 256, 0, stream>>>(Ub, Vb, S);
    k_pairs<<<768, 256, 0, stream>>>(xy, gW1, gb1, gW2, gb2, aW1, ab1, aW2, ab2,
                                     dv, a_geom, a_ang, lsc, S);
}

// Round 10
// 57.156 us; speedup vs baseline: 1.8971x; 1.0073x over previous
//
#include <hip/hip_runtime.h>
#include <math.h>

// ScoreNet: B=8, NV=512, C=256, H=6, R=32, PAIR_H=16, RBF_K=8
// R9 fix: pk2 via inline-asm v_cvt_pk_bf16_f32 (no builtin on gfx950;
//   __hip_bfloat162 not trivially copyable for __builtin_bit_cast).
// R8 structure otherwise unchanged:
//   * k_pairs features computed directly in B-fragment layout (no shuffles)
//   * two independent 32-pair chunks per iteration -> 4 MFMAs in flight
//   * S RMW value prefetched; write pair = base+lane (coalesced)
// k_prep/k_uv/k_gemm unchanged from R7.

#define UK 224

typedef __attribute__((ext_vector_type(8)))  short short8;
typedef __attribute__((ext_vector_type(16))) float f32x16;
typedef __attribute__((ext_vector_type(4)))  int   int4v;

__device__ __forceinline__ float sigmoidf_(float x){ return 1.0f/(1.0f + __expf(-x)); }
__device__ __forceinline__ unsigned f2bf(float x){
    unsigned u = __builtin_bit_cast(unsigned, x);
    return (u + 0x7fffu + ((u>>16)&1u)) >> 16;       // RNE f32->bf16
}
__device__ __forceinline__ unsigned pk2(float lo, float hi){
    unsigned r;
    asm("v_cvt_pk_bf16_f32 %0, %1, %2" : "=v"(r) : "v"(lo), "v"(hi));
    return r;
}
__device__ __forceinline__ f32x16 zero16(){
    f32x16 z;
    #pragma unroll
    for (int i = 0; i < 16; i++) z[i] = 0.f;
    return z;
}

// merged: blocks <4096 pool feats -> bf16 xb; blocks >=4096 pack WT (transposed, bf16) + bcat
__global__ __launch_bounds__(256) void k_prep(const float* __restrict__ feats,
        const float* __restrict__ Wq, const float* __restrict__ Wk,
        const float* __restrict__ Wpi, const float* __restrict__ bpi,
        const float* __restrict__ Wpj, const float* __restrict__ bpj,
        const float* __restrict__ dW, const float* __restrict__ db,
        const float* __restrict__ a_pair,
        unsigned short* __restrict__ xb, unsigned short* __restrict__ WT,
        float* __restrict__ bcat){
    int blk = blockIdx.x, tid = threadIdx.x;
    if (blk < 4096){
        int b = blk >> 9, n = blk & 511;
        size_t base = ((size_t)(b*1025 + 1 + 2*n))*256 + tid;
        float v = 0.5f*(feats[base] + feats[base+256]);
        xb[(size_t)blk*256 + tid] = (unsigned short)f2bf(v);
    } else {
        int col = blk - 4096;    // 0..447
        int c   = tid;           // k index 0..255
        const float invSqrtR = 0.17677669529663687f; // 1/sqrt(32)
        float sp = 1.5f*sigmoidf_(a_pair[0]);
        float v;
        if      (col < 192)  v = Wq[c*192 + col]*invSqrtR;
        else if (col < 208)  v = sp*Wpi[c*16 + (col-192)];
        else if (col < 400)  v = Wk[c*192 + (col-208)];
        else if (col < 416)  v = Wpj[c*16 + (col-400)];
        else if (col == 416) v = dW[c];
        else v = 0.f;
        WT[col*256 + c] = (unsigned short)f2bf(v);
        if (tid == 0){
            float bv = 0.f;
            if      (col >= 192 && col < 208) bv = sp*bpi[col-192];
            else if (col >= 400 && col < 416) bv = bpj[col-400];
            else if (col == 416)              bv = db[0];
            bcat[col] = bv;
        }
    }
}

// xb[4096][256] @ WT^T -> routed to Ub/Vb (bf16, [4096][224], zero-padded) + dv
__global__ __launch_bounds__(256) void k_uv(const unsigned short* __restrict__ xb,
        const unsigned short* __restrict__ WT, const float* __restrict__ bcat,
        unsigned short* __restrict__ Ub, unsigned short* __restrict__ Vb,
        float* __restrict__ dv){
    int tid = threadIdx.x;
    int lane = tid & 63, l31 = lane & 31, hf = lane >> 5;
    int w = tid >> 6, wr = w >> 1, wc = w & 1;
    int c0 = blockIdx.x*64, r0 = blockIdx.y*64;
    const unsigned short* ap = xb + (size_t)(r0 + wr*32 + l31)*256 + 8*hf;
    const unsigned short* bp = WT + (size_t)(c0 + wc*32 + l31)*256 + 8*hf;
    f32x16 acc = zero16();
    #pragma unroll 4
    for (int k0 = 0; k0 < 256; k0 += 16){
        short8 a  = *(const short8*)(ap + k0);
        short8 bb = *(const short8*)(bp + k0);
        acc = __builtin_amdgcn_mfma_f32_32x32x16_bf16(a, bb, acc, 0, 0, 0);
    }
    int col = c0 + wc*32 + l31;          // uniform per lane across all 16 accs
    int rb  = r0 + wr*32 + 4*hf;
    float bc = bcat[col];
    #pragma unroll
    for (int r = 0; r < 16; r++){
        int row = rb + (r&3) + 8*(r>>2);
        float v = acc[r] + bc;
        size_t ui = (size_t)row*UK;
        if (col < 208){
            if (col >= 192) v = fmaxf(v, 0.f);        // a_i relu
            Ub[ui + col] = (unsigned short)f2bf(v);
        } else if (col < 224){
            Vb[ui + col-208] = (unsigned short)f2bf(v);
            Ub[ui + col] = 0;                          // Ub K-pad
        } else if (col < 416){
            if (col >= 400) v = fmaxf(v, 0.f);        // b_j relu
            Vb[ui + col-208] = (unsigned short)f2bf(v);
        } else if (col == 416){
            dv[row] = v;
            Vb[ui + 208] = 0;                          // Vb K-pad
        } else if (col < 432){
            Vb[ui + col-208] = 0;                      // Vb K-pad (cols 417..431 are zero-cols)
        }
        // col >= 432: dead padding, skip
    }
}

// S_lin[b][n][m] = Ub[b,n,:] . Vb[b,m,:]  (bf16 MFMA, K=224 incl. zero pad)
__global__ __launch_bounds__(256) void k_gemm(const unsigned short* __restrict__ Ub,
        const unsigned short* __restrict__ Vb, float* __restrict__ S){
    int tid = threadIdx.x;
    int lane = tid & 63, l31 = lane & 31, hf = lane >> 5;
    int w = tid >> 6, wr = w >> 1, wc = w & 1;
    int b = blockIdx.z;
    int m0 = blockIdx.x*64, n0 = blockIdx.y*64;
    const unsigned short* ap = Ub + (size_t)(b*512 + n0 + wr*32 + l31)*UK + 8*hf;
    const unsigned short* bp = Vb + (size_t)(b*512 + m0 + wc*32 + l31)*UK + 8*hf;
    f32x16 acc = zero16();
    #pragma unroll 2
    for (int k0 = 0; k0 < UK; k0 += 16){
        short8 a  = *(const short8*)(ap + k0);
        short8 bb = *(const short8*)(bp + k0);
        acc = __builtin_amdgcn_mfma_f32_32x32x16_bf16(a, bb, acc, 0, 0, 0);
    }
    int m  = m0 + wc*32 + l31;
    int nb = n0 + wr*32 + 4*hf;
    float* Sp = S + ((size_t)b*512)*512 + m;
    #pragma unroll
    for (int r = 0; r < 16; r++){
        int n = nb + (r&3) + 8*(r>>2);
        Sp[(size_t)n*512] = acc[r];
    }
}

// per-pair geom + angle MLPs via MFMA; in-place RMW on S
// Per iteration: 64 consecutive pairs = 2 chunks of 32. Lane (hf,l31) computes
// chunk-pair (base + chunk*32 + l31) features and packs its OWN k-half:
//   hf=0: (dy,dx)(p0,p1)(p2,p3)(p4,p5)   hf=1: (p6,p7)(c1,s1)(c2,s2)(c4,s4)
// -> B-frag direct, no shuffles. Write pair = base+lane (coalesced 256B RMW).
__global__ __launch_bounds__(256, 3) void k_pairs(const float* __restrict__ xy,
        const float* __restrict__ gW1, const float* __restrict__ gb1,
        const float* __restrict__ gW2, const float* __restrict__ gb2,
        const float* __restrict__ aW1, const float* __restrict__ ab1,
        const float* __restrict__ aW2, const float* __restrict__ ab2,
        const float* __restrict__ dv,
        const float* __restrict__ a_geom, const float* __restrict__ a_ang,
        const float* __restrict__ lsc,
        float* __restrict__ S){
    int tid  = threadIdx.x;
    int lane = tid & 63;
    int hf   = lane >> 5;
    int l31  = lane & 31;

    float sg = 1.5f*sigmoidf_(a_geom[0]);
    float sa = 1.5f*sigmoidf_(a_ang[0]);
    float ls = 0.5f + 2.5f*sigmoidf_(lsc[0]);

    // A-fragments (weights): lane holds A[row=l31][k=hf*8+j]
    short8 wg, wa;
    #pragma unroll
    for (int j = 0; j < 8; j++){
        int f = hf*8 + j;
        float vg = (f < 12) ? gW1[f*32 + l31] : 0.f;
        float va = (f >= 10 && l31 < 16) ? aW1[(f-10)*16 + l31] : 0.f;
        wg[j] = (short)f2bf(vg);
        wa[j] = (short)f2bf(va);
    }

    // per-reg tables: h = (r&3) + 8*(r>>2) + 4*hf  (C/D row of reg r)
    float nbg[16], g2g[16], nba[16], g2a[16];
    float bsum = 0.f;
    #pragma unroll
    for (int r = 0; r < 16; r++){
        int h = (r&3) + 8*(r>>2) + 4*hf;
        float bg  = gb1[h];
        float wg2 = sg*gW2[h];
        nbg[r] = -bg; g2g[r] = wg2; bsum += bg*wg2;
        if (h < 16){
            float ba  = ab1[h];
            float wa2 = sa*aW2[h];
            nba[r] = -ba; g2a[r] = wa2; bsum += ba*wa2;
        } else { nba[r] = 0.f; g2a[r] = 0.f; }
    }
    bsum += __shfl_xor(bsum, 32);
    float cb = sg*gb2[0] + sa*ab2[0] + bsum;

    const float GAMMA = 12.2499985f;    // 1/(2*spacing^2 + 1e-8)
    const float TWOGD = 4.9497469f;     // 2*GAMMA*spacing

    int wid = __builtin_amdgcn_readfirstlane(tid >> 6);
    int wave_g = blockIdx.x*4 + wid;            // 768*4 = 3072 waves
    for (int c = wave_g; c < 32768; c += 3072){
        int base = c*64;
        int nn = (base >> 9) & 511;             // wave-uniform
        int bb = base >> 18;                    // wave-uniform
        const float* xyb = xy + (size_t)bb*1024;
        float yn = xyb[2*nn], xn = xyb[2*nn+1];
        bool padn = (fabsf(yn) < 1e-9f) && (fabsf(xn) < 1e-9f);
        float sv  = S[(size_t)base + lane];     // prefetch RMW value (coalesced)
        float dvn = dv[bb*512 + nn];

        unsigned fA0, fA1, fA2, fA3, fB0, fB1, fB2, fB3;
        float mA, mB;
        #pragma unroll
        for (int ch = 0; ch < 2; ch++){
            int pidx = base + ch*32 + l31;
            float2 pm = *(const float2*)(xyb + 2*(pidx & 511));
            float ym = pm.x, xm = pm.y;
            bool padm = (fabsf(ym) < 1e-9f) && (fabsf(xm) < 1e-9f);
            float msk = (padn || padm) ? 0.f : 1.f;
            float dy = yn - ym, dx = xn - xm;
            float r2 = dy*dy + dx*dx;
            float re = sqrtf(r2 + 1e-8f);
            float c1, s1;
            if (r2 > 0.f){ float inv = rsqrtf(r2); c1 = dx*inv; s1 = dy*inv; }
            else { c1 = 1.f; s1 = 0.f; }        // atan2(0,0)=0
            float c2 = c1*c1 - s1*s1, s2 = 2.f*c1*s1;
            float c4 = c2*c2 - s2*s2, s4 = 2.f*c2*s2;
            float e0 = __expf(-GAMMA*(r2 + 1e-8f));
            float E  = __expf(TWOGD*re);
            float u  = e0;
            float p0 = u;
            u *= E; float p1 = 0.60653066f*u;
            u *= E; float p2 = 0.13533528f*u;
            u *= E; float p3 = 0.011108997f*u;
            u *= E; float p4 = 3.3546263e-4f*u;
            u *= E; float p5 = 3.7266532e-6f*u;
            u *= E; float p6 = 1.5229979e-8f*u;
            u *= E; float p7 = 2.2897348e-11f*u;
            unsigned w0 = hf ? pk2(p6, p7) : pk2(dy, dx);
            unsigned w1 = hf ? pk2(c1, s1) : pk2(p0, p1);
            unsigned w2 = hf ? pk2(c2, s2) : pk2(p2, p3);
            unsigned w3 = hf ? pk2(c4, s4) : pk2(p4, p5);
            if (ch == 0){ fA0=w0; fA1=w1; fA2=w2; fA3=w3; mA = msk; }
            else        { fB0=w0; fB1=w1; fB2=w2; fB3=w3; mB = msk; }
        }
        int4v ivA = {(int)fA0, (int)fA1, (int)fA2, (int)fA3};
        int4v ivB = {(int)fB0, (int)fB1, (int)fB2, (int)fB3};
        short8 bfA = __builtin_bit_cast(short8, ivA);
        short8 bfB = __builtin_bit_cast(short8, ivB);

        f32x16 z = zero16();
        f32x16 dgA = __builtin_amdgcn_mfma_f32_32x32x16_bf16(wg, bfA, z, 0, 0, 0);
        f32x16 dgB = __builtin_amdgcn_mfma_f32_32x32x16_bf16(wg, bfB, z, 0, 0, 0);
        f32x16 daA = __builtin_amdgcn_mfma_f32_32x32x16_bf16(wa, bfA, z, 0, 0, 0);
        f32x16 daB = __builtin_amdgcn_mfma_f32_32x32x16_bf16(wa, bfB, z, 0, 0, 0);

        float accA = 0.f, accB = 0.f;
        #pragma unroll
        for (int r = 0; r < 16; r++){
            accA += fmaxf(dgA[r], nbg[r]) * g2g[r];
            accB += fmaxf(dgB[r], nbg[r]) * g2g[r];
        }
        #pragma unroll
        for (int r = 0; r < 16; r++){
            accA += fmaxf(daA[r], nba[r]) * g2a[r];
            accB += fmaxf(daB[r], nba[r]) * g2a[r];
        }
        accA += __shfl_xor(accA, 32);
        accB += __shfl_xor(accB, 32);

        float res  = (lane < 32) ? accA : accB;   // write pair = base+lane
        float mskw = (lane < 32) ? mA : mB;
        int m_w = (base + lane) & 511;
        float ddg = (m_w == nn) ? dvn : 0.f;
        S[(size_t)base + lane] = (sv + mskw*(res + cb) + ddg) * ls;
    }
}

extern "C" void kernel_launch(void* const* d_in, const int* in_sizes, int n_in,
                              void* d_out, int out_size, void* d_ws, size_t ws_size,
                              hipStream_t stream){
    const float* feats = (const float*)d_in[0];
    const float* xy    = (const float*)d_in[1];
    const float* Wq    = (const float*)d_in[2];
    const float* Wk    = (const float*)d_in[3];
    const float* Wpi   = (const float*)d_in[4];
    const float* bpi   = (const float*)d_in[5];
    const float* Wpj   = (const float*)d_in[6];
    const float* bpj   = (const float*)d_in[7];
    const float* gW1   = (const float*)d_in[8];
    const float* gb1   = (const float*)d_in[9];
    const float* gW2   = (const float*)d_in[10];
    const float* gb2   = (const float*)d_in[11];
    const float* aW1   = (const float*)d_in[12];
    const float* ab1   = (const float*)d_in[13];
    const float* aW2   = (const float*)d_in[14];
    const float* ab2   = (const float*)d_in[15];
    const float* dW    = (const float*)d_in[16];
    const float* db    = (const float*)d_in[17];
    const float* a_pair= (const float*)d_in[18];
    const float* a_geom= (const float*)d_in[19];
    const float* a_ang = (const float*)d_in[20];
    const float* lsc   = (const float*)d_in[21];

    float* S = (float*)d_out;
    char* wsb = (char*)d_ws;
    unsigned short* xb = (unsigned short*)wsb;                    // 4096*256*2 = 2,097,152 B
    unsigned short* WT = (unsigned short*)(wsb + 2097152);        // 448*256*2  =   229,376 B
    unsigned short* Ub = (unsigned short*)(wsb + 2326528);        // 4096*224*2 = 1,835,008 B
    unsigned short* Vb = (unsigned short*)(wsb + 4161536);        // 1,835,008 B
    float* bcat = (float*)(wsb + 5996544);                        // 448*4
    float* dv   = (float*)(wsb + 5998336);                        // 4096*4
    // total ~6.0 MB of d_ws

    k_prep <<<4544, 256, 0, stream>>>(feats, Wq, Wk, Wpi, bpi, Wpj, bpj, dW, db, a_pair,
                                      xb, WT, bcat);
    k_uv   <<<dim3(7,64), 256, 0, stream>>>(xb, WT, bcat, Ub, Vb, dv);
    k_gemm <<<dim3(8,8,8), 256, 0, stream>>>(Ub, Vb, S);
    k_pairs<<<768, 256, 0, stream>>>(xy, gW1, gb1, gW2, gb2, aW1, ab1, aW2, ab2,
                                     dv, a_geom, a_ang, lsc, S);
}